// Round 20
// baseline (184.299 us; speedup 1.0000x reference)
//
#include <hip/hip_runtime.h>
#include <hip/hip_fp16.h>
#include <math.h>

#define N_TOKENS 16384
#define D_MODEL  2048
#define NE       64
#define TOPK     8

typedef float    f32x4 __attribute__((ext_vector_type(4)));
typedef _Float16 f16x8 __attribute__((ext_vector_type(8)));
typedef short    s16x8 __attribute__((ext_vector_type(8)));

#define WSCL   512.0f              // B pre-scale (keeps Bm out of f16 denormals)
#define XSCL   1024.0f             // x pre-scale (keeps Am out of f16 denormals)
#define UNSCL  (1.0 / (1024.0 * 512.0))   // exact 2^-19

// Pre-pass (validated R19): coalesced reads, thread = (k, j).
// Layout: BF[((c*8+ct)*2+s)*64 + l][e8], l = l_hi*16 + l_lo,
// c=k>>5, kk=k&31, l_hi=kk>>3, e8=kk&7, ct=j>>4, l_lo=j&15.
__global__ __launch_bounds__(256)
void bf_build(const float* __restrict__ Wg, const float* __restrict__ Wn,
              short* __restrict__ BFs) {
    const int id = blockIdx.x * 256 + threadIdx.x;   // 0..262143
    const int k  = id >> 7;        // 0..2047
    const int j  = id & 127;       // 0..127
    const float w = (j < NE) ? Wg[(size_t)k * NE + j] : Wn[(size_t)k * NE + (j - NE)];
    const float v = w * WSCL;
    __half h = __float2half(v);                        // RNE
    __half m = __float2half(v - __half2float(h));      // exact residual (Sterbenz)
    const int c = k >> 5, kk = k & 31;
    const int l_hi = kk >> 3, e8 = kk & 7;
    const int ct = j >> 4, l_lo = j & 15;
    const size_t base = ((size_t)((c * 8 + ct) * 2) * 64 + l_hi * 16 + l_lo) * 8 + e8;
    BFs[base]       = __half_as_short(h);
    BFs[base + 512] = __half_as_short(m);   // s=1 plane is +64 words = +512 shorts
}

// ---------------- Kernel A: barrier-free, LDS-free GEMM ----------------
// One 16x16 output tile per wave; A-fragments built in-register from
// per-lane x loads (lane (l&15)=row, (l>>4)*8=k-slot -> the wave's 64 lanes
// consume exactly one 128B line per row per chunk). No __shared__, no
// s_barrier: waves are fully independent streams so 5+/SIMD TLP hides
// the L2/L3 latency the R12-R19 barrier convoys kept exposing.
__global__ __launch_bounds__(512, 5)
void router_gemm(const float* __restrict__ x, const s16x8* __restrict__ BF,
                 float* __restrict__ dots)    // [N_TOKENS][128] fp32
{
    const int tid  = threadIdx.x;
    const int lane = tid & 63;
    const int wv   = tid >> 6;            // wave id = ctile 0..7 (16 cols each)
    const int row0 = blockIdx.x * 16;     // block = 1 token tile, 8 ctile-waves

    // per-lane A source: row = row0 + (lane&15), k-slot = (lane>>4)*8
    const float* xbase = x + (size_t)(row0 + (lane & 15)) * D_MODEL + ((lane >> 4) * 8);
    const f16x8* bfp = (const f16x8*)BF + lane;

    auto loadB = [&](int c, f16x8& bh, f16x8& bm) {
        const f16x8* p = bfp + (size_t)((c * 8 + wv) * 2) * 64;
        bh = p[0];
        bm = p[64];
    };
    auto loadX = [&](int c, float4& a0, float4& a1) {
        const float4* p = (const float4*)(xbase + c * 32);
        a0 = p[0];
        a1 = p[1];
    };
    // identical arithmetic to the R16-R19 convert_store (same RNE split,
    // same values per (row,k)) -> bit-identical A fragments.
    auto convert = [&](float4 a0, float4 a1, f16x8& Ah, f16x8& Am) {
        float vv[8] = {a0.x, a0.y, a0.z, a0.w, a1.x, a1.y, a1.z, a1.w};
        #pragma unroll
        for (int e = 0; e < 8; ++e) {
            float v = vv[e] * XSCL;                    // exact pow2 scale
            _Float16 h = (_Float16)v;                  // RNE
            float r = v - (float)h;                    // exact (Sterbenz)
            Ah[e] = h;
            Am[e] = (_Float16)r;
        }
    };

    f32x4 Ca = {0.f,0.f,0.f,0.f}, Cb = Ca;
    double facc[4] = {0.0, 0.0, 0.0, 0.0};

    // prologue: x and B for chunks 0,1 in flight
    float4 xa0, xa1, xb0, xb1;
    f16x8 BAh, BAm, BBh, BBm;
    loadX(0, xa0, xa1);
    loadX(1, xb0, xb1);
    loadB(0, BAh, BAm);
    loadB(1, BBh, BBm);

    // main loop: 2 chunks per iteration; reload each register slot right
    // after its consumer (distance ~1.5-2 chunks; TLP covers the rest).
    #pragma unroll 1
    for (int c = 0; c < 64; c += 2) {
        f16x8 Ah, Am;

        convert(xa0, xa1, Ah, Am);
        if (c + 2 < 64) loadX(c + 2, xa0, xa1);
        Ca = __builtin_amdgcn_mfma_f32_16x16x32_f16(Am, BAh, Ca, 0, 0, 0); // mh
        Cb = __builtin_amdgcn_mfma_f32_16x16x32_f16(Ah, BAm, Cb, 0, 0, 0); // hm
        Ca = __builtin_amdgcn_mfma_f32_16x16x32_f16(Ah, BAh, Ca, 0, 0, 0); // hh
        if (c + 2 < 64) loadB(c + 2, BAh, BAm);

        convert(xb0, xb1, Ah, Am);
        if (c + 3 < 64) loadX(c + 3, xb0, xb1);
        Ca = __builtin_amdgcn_mfma_f32_16x16x32_f16(Am, BBh, Ca, 0, 0, 0); // mh
        Cb = __builtin_amdgcn_mfma_f32_16x16x32_f16(Ah, BBm, Cb, 0, 0, 0); // hm
        Ca = __builtin_amdgcn_mfma_f32_16x16x32_f16(Ah, BBh, Ca, 0, 0, 0); // hh
        if (c + 3 < 64) loadB(c + 3, BBh, BBm);

        #pragma unroll
        for (int j = 0; j < 4; ++j) {      // fp64 fold every 64 k (cadence = R12-R19)
            facc[j] += (double)Ca[j] + (double)Cb[j];
            Ca[j] = 0.f; Cb[j] = 0.f;
        }
    }

    // write fp32 dots (unscale by exact 2^-19)
    const int ocol = wv * 16 + (lane & 15);
    #pragma unroll
    for (int j = 0; j < 4; ++j)
        dots[(size_t)(row0 + (lane >> 4) * 4 + j) * 128 + ocol]
            = (float)(facc[j] * UNSCL);
}

// ---------------- Kernel B: softplus + noise + top-8 + sparse softmax ----------------
// Byte-identical to R17/R19 (proven): one wave per token, fp64 selection path.
__global__ __launch_bounds__(512)
void router_topk(const float* __restrict__ dots, const float* __restrict__ eps,
                 const float* __restrict__ bg, const float* __restrict__ bn,
                 float* __restrict__ out_probs, float* __restrict__ out_idx)
{
    const int tid  = threadIdx.x;
    const int lane = tid & 63;
    const int wv   = tid >> 6;
    const int tok  = blockIdx.x * 8 + wv;

    const double logit = (double)dots[(size_t)tok * 128 + lane]      + (double)bg[lane];
    const double nvv   = (double)dots[(size_t)tok * 128 + 64 + lane] + (double)bn[lane];
    const double sp    = (nvv > 0.0) ? (nvv + log1p(exp(-nvv))) : log1p(exp(nvv));
    const double noisy = logit + (double)eps[(size_t)tok * NE + lane] * sp;

    // iterative top-8; tie-break: higher value, then lower index (lax.top_k)
    double cur = noisy;
    double m = 0.0, sum = 0.0;
    int    sel = 0;
    float  my_idx = 0.0f;
    #pragma unroll
    for (int rk = 0; rk < TOPK; ++rk) {
        double bv = cur;
        int    bi = lane;
        #pragma unroll
        for (int off = 32; off >= 1; off >>= 1) {
            double ov = __shfl_xor(bv, off);
            int    oi = __shfl_xor(bi, off);
            if (ov > bv || (ov == bv && oi < bi)) { bv = ov; bi = oi; }
        }
        if (rk == 0) m = bv;
        sum += exp(bv - m);
        if (lane == bi) { sel = 1; cur = -INFINITY; }
        if (lane == rk) my_idx = (float)bi;
    }

    out_probs[(size_t)tok * NE + lane] = (float)(sel ? exp(noisy - m) / sum : 0.0);
    if (lane < TOPK) out_idx[(size_t)tok * TOPK + lane] = my_idx;
}

extern "C" void kernel_launch(void* const* d_in, const int* in_sizes, int n_in,
                              void* d_out, int out_size, void* d_ws, size_t ws_size,
                              hipStream_t stream) {
    const float* x   = (const float*)d_in[0];
    const float* eps = (const float*)d_in[1];
    const float* Wg  = (const float*)d_in[2];
    const float* bg  = (const float*)d_in[3];
    const float* Wn  = (const float*)d_in[4];
    const float* bn  = (const float*)d_in[5];

    float* out_probs = (float*)d_out;                              // [N, E]
    float* out_idx   = (float*)d_out + (size_t)N_TOKENS * NE;      // [N, K]

    // d_ws layout: BF fragments (1 MB) | dots fp32 [16384][128] (8 MB)
    s16x8* BF   = (s16x8*)d_ws;
    float* dots = (float*)((char*)d_ws + (size_t)65536 * 16);

    bf_build<<<dim3(1024), dim3(256), 0, stream>>>(Wg, Wn, (short*)BF);

    router_gemm<<<dim3(N_TOKENS / 16), dim3(512), 0, stream>>>(x, BF, dots);

    router_topk<<<dim3(N_TOKENS / 8), dim3(512), 0, stream>>>(
        dots, eps, bg, bn, out_probs, out_idx);
}